// Round 4
// baseline (108.337 us; speedup 1.0000x reference)
//
#include <hip/hip_runtime.h>
#include <hip/hip_bf16.h>

// SingleDimHistLayer: soft histogram via fine-grid deposit + 145-tap convolution.
//
// Math: out[b,k] = (1/N) * sum_n [ g(u_n - k) - g(u_n - k - 1) ],  g(v)=sigmoid(2.5 v),
//       u = x*256.  Terms negligible outside |u - k - 0.5| <= 4.5 -> 145 fine taps
//       at 1/16 resolution.  Fine index p = round(x*4096) + 64, p in [0,4224].
//
// Round 4: pipe-split probe. Decomposition (2x confirmed): dur ~= 41.4us harness
// ws-poison fill + ~18.4us ours, of which deposit ~10us at the DS-pipe lane-serial
// floor (~3cyc/atomic/CU, wave-count-invariant per rounds 0->1). Coop launch
// regressed +32us (round 3) -> reverted. This round routes HALF the samples to
// per-batch GLOBAL fine-hist atomics (TCC pipe, L2-resident 139KB) concurrent
// with the LDS-atomic half (DS pipe). Per-block conv covers the LDS half only;
// the reduce kernel convolves the global half and adds partials.

constexpr int KBINS   = 256;
constexpr int FSUB    = 16;                  // fine nodes per bin
constexpr int LPAD    = 64;                  // left halo (k=0 window reaches f=-64)
constexpr int TAPS    = 145;                 // window f in [16k-64, 16k+80]
// bank-skew addressing for LDS: addr = p + (p>>5); max logical p = 4224 -> 4356
constexpr int LDS_FH  = 4360;
constexpr int NPB     = 512 * 512;           // samples per batch
constexpr int BLK_PER_BATCH = 32;            // 8192 samples per block, grid = 256
constexpr int CHUNK   = NPB / BLK_PER_BATCH; // 8192
constexpr int THREADS = 1024;                // 16 waves/CU
constexpr int GH_STRIDE = 4352;              // per-batch global fine hist (u32), padded

__device__ __forceinline__ int skew(int p) { return p + (p >> 5); }

__global__ __launch_bounds__(THREADS)
void hist_kernel(const float* __restrict__ x, unsigned* __restrict__ gh,
                 float* __restrict__ partials) {
    __shared__ unsigned fh[LDS_FH];
    __shared__ float w[TAPS];
    const int tid = threadIdx.x;

    // zero fine hist
    for (int i = tid; i < LDS_FH; i += THREADS) fh[i] = 0u;

    // conv weights: w[j] = sigmoid(0.15625*(j-64)) - sigmoid(0.15625*(j-80))
    if (tid < TAPS) {
        float a = 0.15625f * (float)(tid - 64);
        float b = 0.15625f * (float)(tid - 80);
        w[tid] = 1.f / (1.f + __expf(-a)) - 1.f / (1.f + __expf(-b));
    }
    __syncthreads();

    const int b     = blockIdx.x / BLK_PER_BATCH;
    const int chunk = blockIdx.x % BLK_PER_BATCH;
    const float4* xv = (const float4*)(x + (size_t)b * NPB + (size_t)chunk * CHUNK);
    unsigned* ghb = gh + (size_t)b * GH_STRIDE;

    // deposit: 8 samples/thread; per float4, 2 go to LDS (DS pipe) and
    // 2 go to the per-batch global fine hist (TCC pipe) -> both pipes busy.
    #pragma unroll
    for (int it = 0; it < CHUNK / (4 * THREADS); ++it) {
        float4 v = xv[it * THREADS + tid];
        float vals[4] = {v.x, v.y, v.z, v.w};
        int p[4];
        #pragma unroll
        for (int c = 0; c < 4; ++c) {
            float s = fmaf(vals[c], (float)(KBINS * FSUB), (float)LPAD + 0.5f);
            s = fminf(fmaxf(s, 0.f), 4224.f);            // defensive clamp (NaN -> 0)
            p[c] = (int)s;
        }
        atomicAdd(&fh[skew(p[0])], 1u);
        atomicAdd(&ghb[p[2]], 1u);
        atomicAdd(&fh[skew(p[1])], 1u);
        atomicAdd(&ghb[p[3]], 1u);
    }
    __syncthreads();

    // convolve LDS half: 4 threads per coarse bin, ~36 taps each, shfl reduce.
    // bin k reads padded fine nodes [16k, 16k+144].
    {
        const int bin = tid >> 2;          // 0..255
        const int q   = tid & 3;
        const int j0  = q * 37;
        const int j1  = (j0 + 37 < TAPS) ? j0 + 37 : TAPS;
        const int base = bin * FSUB;
        float acc = 0.f;
        #pragma unroll 4
        for (int j = j0; j < j1; ++j)
            acc += w[j] * (float)fh[skew(base + j)];
        acc += __shfl_xor(acc, 1);
        acc += __shfl_xor(acc, 2);
        // non-atomic partial write: each (block, bin) slot written exactly once
        if (q == 0)
            partials[(size_t)blockIdx.x * KBINS + bin] = acc;
    }
}

// Per batch: conv the global fine hist + sum the 32 LDS partials, apply 1/N.
__global__ __launch_bounds__(KBINS)
void reduce_kernel(const unsigned* __restrict__ gh, const float* __restrict__ partials,
                   float* __restrict__ out) {
    __shared__ float w[TAPS];
    const int b = blockIdx.x;
    const int k = threadIdx.x;
    if (k < TAPS) {
        float a = 0.15625f * (float)(k - 64);
        float c = 0.15625f * (float)(k - 80);
        w[k] = 1.f / (1.f + __expf(-a)) - 1.f / (1.f + __expf(-c));
    }
    __syncthreads();

    float acc = 0.f;
    const unsigned* g = gh + (size_t)b * GH_STRIDE + k * FSUB;  // max idx 4224 < 4352
    #pragma unroll 8
    for (int j = 0; j < TAPS; ++j)
        acc += w[j] * (float)g[j];

    const float* p = partials + (size_t)b * BLK_PER_BATCH * KBINS + k;
    #pragma unroll
    for (int c = 0; c < BLK_PER_BATCH; ++c)
        acc += p[(size_t)c * KBINS];

    out[b * KBINS + k] = acc * (1.f / (float)NPB);
}

extern "C" void kernel_launch(void* const* d_in, const int* in_sizes, int n_in,
                              void* d_out, int out_size, void* d_ws, size_t ws_size,
                              hipStream_t stream) {
    const float* x = (const float*)d_in[0];
    float* out = (float*)d_out;
    const int B = in_sizes[0] / NPB;   // 8

    unsigned* gh = (unsigned*)d_ws;                          // B*4352 u32 = 139 KB
    float* partials = (float*)d_ws + (size_t)B * GH_STRIDE;  // B*32*256 f32 = 256 KB

    hipMemsetAsync(d_ws, 0, (size_t)B * GH_STRIDE * sizeof(unsigned), stream);
    hist_kernel<<<B * BLK_PER_BATCH, THREADS, 0, stream>>>(x, gh, partials);
    reduce_kernel<<<B, KBINS, 0, stream>>>(gh, partials, out);
}

// Round 5
// 81.717 us; speedup vs baseline: 1.3258x; 1.3258x over previous
//
#include <hip/hip_runtime.h>
#include <hip/hip_bf16.h>

// SingleDimHistLayer: soft histogram via fine-grid deposit + 145-tap convolution.
//
// Math: out[b,k] = (1/N) * sum_n [ g(u_n - k) - g(u_n - k - 1) ],  g(v)=sigmoid(2.5 v),
//       u = x*256.  Terms negligible outside |u - k - 0.5| <= 4.5 -> 145 fine taps
//       at 1/16 resolution.  Fine index p = round(x*4096) + 64, p in [0,4224].
//
// Round 5: pipe-split probe v2, risk-bounded. Round 4 (shared global hist,
// device-scope atomics) measured 28 Gat/s -> +35us. Two theories: cross-XCD
// line ping-pong (fix: per-BLOCK private copies) or device-scope forced to a
// slow memory-side coherence point (fix: workgroup-scope atomics, legal on
// private data). This probe applies BOTH fixes at a 25% split (1 of 4 samples
// -> private global copy, 3 -> LDS). Blocks zero their own copy in-kernel and
// merge it back into the LDS hist post-barrier (agent-scope loads to bypass
// stale write-through L1 lines). Conv/reduce/dispatch structure = round 2.
// Fast path  -> dur ~57.5 (then push split harder next round).
// Slow path  -> dur ~65-68 (decisive: abandon second-pipe line).

constexpr int KBINS   = 256;
constexpr int FSUB    = 16;                  // fine nodes per bin
constexpr int LPAD    = 64;                  // left halo (k=0 window reaches f=-64)
constexpr int TAPS    = 145;                 // window f in [16k-64, 16k+80]
// bank-skew addressing for LDS: addr = p + (p>>5); max logical p = 4224 -> 4356
constexpr int LDS_FH  = 4360;
constexpr int NPB     = 512 * 512;           // samples per batch
constexpr int BLK_PER_BATCH = 32;            // 8192 samples per block, grid = 256
constexpr int CHUNK   = NPB / BLK_PER_BATCH; // 8192
constexpr int THREADS = 1024;                // 16 waves/CU
constexpr int PFINE   = 4225;                // logical fine nodes (p in [0,4224])
constexpr int GH_WORDS = 4352;               // per-BLOCK private global hist stride

__device__ __forceinline__ int skew(int p) { return p + (p >> 5); }

__global__ __launch_bounds__(THREADS)
void hist_kernel(const float* __restrict__ x, unsigned* __restrict__ gh,
                 float* __restrict__ partials) {
    __shared__ unsigned fh[LDS_FH];
    __shared__ float w[TAPS];
    const int tid = threadIdx.x;
    unsigned* ghb = gh + (size_t)blockIdx.x * GH_WORDS;   // block-private copy

    // zero LDS fine hist + own global copy (write-through stores; drained at barrier)
    for (int i = tid; i < LDS_FH; i += THREADS) fh[i] = 0u;
    for (int i = tid; i < GH_WORDS; i += THREADS) ghb[i] = 0u;

    // conv weights: w[j] = sigmoid(0.15625*(j-64)) - sigmoid(0.15625*(j-80))
    if (tid < TAPS) {
        float a = 0.15625f * (float)(tid - 64);
        float b = 0.15625f * (float)(tid - 80);
        w[tid] = 1.f / (1.f + __expf(-a)) - 1.f / (1.f + __expf(-b));
    }
    __syncthreads();

    const int b     = blockIdx.x / BLK_PER_BATCH;
    const int chunk = blockIdx.x % BLK_PER_BATCH;
    const float4* xv = (const float4*)(x + (size_t)b * NPB + (size_t)chunk * CHUNK);

    // deposit: 8 samples/thread; per float4, 3 -> LDS atomics (DS pipe),
    // 1 -> block-private global hist, workgroup-scope (TCC pipe, own-XCD L2).
    #pragma unroll
    for (int it = 0; it < CHUNK / (4 * THREADS); ++it) {
        float4 v = xv[it * THREADS + tid];
        float vals[4] = {v.x, v.y, v.z, v.w};
        int p[4];
        #pragma unroll
        for (int c = 0; c < 4; ++c) {
            float s = fmaf(vals[c], (float)(KBINS * FSUB), (float)LPAD + 0.5f);
            s = fminf(fmaxf(s, 0.f), 4224.f);            // defensive clamp (NaN -> 0)
            p[c] = (int)s;
        }
        atomicAdd(&fh[skew(p[0])], 1u);
        atomicAdd(&fh[skew(p[1])], 1u);
        atomicAdd(&fh[skew(p[2])], 1u);
        (void)__hip_atomic_fetch_add(&ghb[p[3]], 1u, __ATOMIC_RELAXED,
                                     __HIP_MEMORY_SCOPE_WORKGROUP);
    }
    __syncthreads();   // drains vmcnt -> all private-copy atomics landed in L2

    // merge private global copy into LDS hist. Agent-scope load bypasses the
    // write-through L1 (which holds stale zero lines from our own zeroing).
    for (int p = tid; p < PFINE; p += THREADS) {
        unsigned c = __hip_atomic_load(&ghb[p], __ATOMIC_RELAXED,
                                       __HIP_MEMORY_SCOPE_AGENT);
        fh[skew(p)] += c;   // distinct p per thread -> race-free
    }
    __syncthreads();

    // convolve: 4 threads per coarse bin, ~36 taps each, shfl pair-reduce.
    // bin k reads padded fine nodes [16k, 16k+144].
    {
        const int bin = tid >> 2;          // 0..255
        const int q   = tid & 3;
        const int j0  = q * 37;
        const int j1  = (j0 + 37 < TAPS) ? j0 + 37 : TAPS;
        const int base = bin * FSUB;
        float acc = 0.f;
        #pragma unroll 4
        for (int j = j0; j < j1; ++j)
            acc += w[j] * (float)fh[skew(base + j)];
        acc += __shfl_xor(acc, 1);
        acc += __shfl_xor(acc, 2);
        // non-atomic partial write: each (block, bin) slot written exactly once
        if (q == 0)
            partials[(size_t)blockIdx.x * KBINS + bin] = acc;
    }
}

// reduce 32 per-chunk partials per batch -> out[b,k], apply 1/N
__global__ __launch_bounds__(KBINS)
void reduce_kernel(const float* __restrict__ partials, float* __restrict__ out) {
    const int b = blockIdx.x;
    const int k = threadIdx.x;
    const float* p = partials + (size_t)b * BLK_PER_BATCH * KBINS + k;
    float s = 0.f;
    #pragma unroll
    for (int c = 0; c < BLK_PER_BATCH; ++c)
        s += p[(size_t)c * KBINS];
    out[b * KBINS + k] = s * (1.f / (float)NPB);
}

extern "C" void kernel_launch(void* const* d_in, const int* in_sizes, int n_in,
                              void* d_out, int out_size, void* d_ws, size_t ws_size,
                              hipStream_t stream) {
    const float* x = (const float*)d_in[0];
    float* out = (float*)d_out;
    const int B = in_sizes[0] / NPB;   // 8

    unsigned* gh = (unsigned*)d_ws;                              // 256*4352*4 = 4.46 MB
    float* partials = (float*)d_ws + (size_t)B * BLK_PER_BATCH * GH_WORDS;  // +256 KB

    hist_kernel<<<B * BLK_PER_BATCH, THREADS, 0, stream>>>(x, gh, partials);
    reduce_kernel<<<B, KBINS, 0, stream>>>(partials, out);
}

// Round 6
// 66.822 us; speedup vs baseline: 1.6213x; 1.2229x over previous
//
#include <hip/hip_runtime.h>
#include <hip/hip_bf16.h>

// SingleDimHistLayer: soft histogram via fine-grid deposit + 145-tap convolution.
//
// Math: out[b,k] = (1/N) * sum_n [ g(u_n - k) - g(u_n - k - 1) ],  g(v)=sigmoid(2.5 v),
//       u = x*256.  Terms negligible outside |u - k - 0.5| <= 4.5 -> 145 fine taps
//       at 1/16 resolution.  Fine index p = round(x*4096) + 64, p in [0,4224].
//
// Round 6: ATOMIC-FREE deposit. Global atomics are structurally ~25 Gat/s
// (rounds 4+5, scope/sharing-independent) -> dead end. LDS ds_add is lane-serial
// ~195cyc/wave-op -> the old ~10.4us deposit floor. This round: per-WAVE private
// u16 histograms (16 x 4360 x 2B = 139.5KB of the 160KB LDS) -> no inter-wave
// races; intra-wave same-bin collisions resolved in-register via 13-bit ballot
// match (leader adds popcount with plain u16 read/write; same-wave DS ops are
// ordered). u16 rows provably can't overflow (<=512 samples/wave). Post-barrier
// merge: uint2 reads, u32 adds (no cross-half carry: max 8192), into the skewed
// u32 hist; conv + partials + reduce kernel unchanged from round 2 (59.8us).

constexpr int KBINS   = 256;
constexpr int FSUB    = 16;                  // fine nodes per bin
constexpr int LPAD    = 64;                  // left halo (k=0 window reaches f=-64)
constexpr int TAPS    = 145;                 // window f in [16k-64, 16k+80]
// skewed u32 merged hist: addr = p + (p>>5); merge writes p<=4227 -> skew 4359
constexpr int LDS_FH  = 4360;
constexpr int NPB     = 512 * 512;           // samples per batch
constexpr int BLK_PER_BATCH = 32;            // 8192 samples per block, grid = 256
constexpr int CHUNK   = NPB / BLK_PER_BATCH; // 8192
constexpr int THREADS = 1024;                // 16 waves, 1 block/CU (LDS-limited)
constexpr int NWAVES  = THREADS / 64;        // 16
constexpr int ROWB    = 4360;                // per-wave row (u16), mult of 4

__device__ __forceinline__ int skew(int p) { return p + (p >> 5); }

__global__ __launch_bounds__(THREADS)
void hist_kernel(const float* __restrict__ x, float* __restrict__ partials) {
    __shared__ __align__(16) unsigned short fh16[NWAVES][ROWB];  // 139.5 KB
    __shared__ unsigned fhs[LDS_FH];                             // 17.4 KB (merged)
    __shared__ float w[TAPS];
    const int tid  = threadIdx.x;
    const int lane = tid & 63;
    unsigned short* fw = &fh16[tid >> 6][0];

    // prefetch this thread's 8 samples before the init barrier (hides HBM latency)
    const int b     = blockIdx.x / BLK_PER_BATCH;
    const int chunk = blockIdx.x % BLK_PER_BATCH;
    const float4* xv = (const float4*)(x + (size_t)b * NPB + (size_t)chunk * CHUNK);
    const float4 v0 = xv[tid];
    const float4 v1 = xv[THREADS + tid];

    // zero per-wave hists (vectorized: 34880 u32 = 8720 uint4)
    {
        uint4* z = (uint4*)&fh16[0][0];
        for (int i = tid; i < (NWAVES * ROWB) / 8; i += THREADS)
            z[i] = make_uint4(0u, 0u, 0u, 0u);
    }
    // conv weights: w[j] = sigmoid(0.15625*(j-64)) - sigmoid(0.15625*(j-80))
    if (tid < TAPS) {
        float a = 0.15625f * (float)(tid - 64);
        float c = 0.15625f * (float)(tid - 80);
        w[tid] = 1.f / (1.f + __expf(-a)) - 1.f / (1.f + __expf(-c));
    }
    __syncthreads();

    // deposit: 8 samples/thread into the wave-private u16 row, atomic-free.
    // Equal-bin lanes within the wave are found via 13 ballots; the group
    // leader adds popcount. Same-wave DS ops are ordered -> slot-to-slot safe.
    {
        const float vals[8] = {v0.x, v0.y, v0.z, v0.w, v1.x, v1.y, v1.z, v1.w};
        #pragma unroll
        for (int c = 0; c < 8; ++c) {
            float s = fmaf(vals[c], (float)(KBINS * FSUB), (float)LPAD + 0.5f);
            s = fminf(fmaxf(s, 0.f), 4224.f);            // defensive clamp (NaN -> 0)
            const int p = (int)s;
            unsigned long long m = ~0ull;
            #pragma unroll
            for (int bit = 0; bit < 13; ++bit) {         // p < 8192
                const unsigned long long bl = __ballot((p >> bit) & 1);
                m &= ((p >> bit) & 1) ? bl : ~bl;
            }
            if (lane == __ffsll((long long)m) - 1)
                fw[p] = (unsigned short)(fw[p] + (unsigned)__popcll(m));
        }
    }
    __syncthreads();

    // merge 16 wave rows -> skewed u32 hist. uint2 = 4 u16; u32 adds are safe
    // (each 16-bit half sums to <= 8192, no carry across halves).
    // Covers p in [0, 4227]: every slot conv reads (p <= 4224) is written.
    for (int t = tid; t < 1057; t += THREADS) {
        unsigned sx = 0u, sy = 0u;
        #pragma unroll
        for (int wv = 0; wv < NWAVES; ++wv) {
            const uint2 v = *(const uint2*)&fh16[wv][4 * t];
            sx += v.x; sy += v.y;
        }
        const int p = 4 * t;
        fhs[skew(p + 0)] = sx & 0xFFFFu;
        fhs[skew(p + 1)] = sx >> 16;
        fhs[skew(p + 2)] = sy & 0xFFFFu;
        fhs[skew(p + 3)] = sy >> 16;
    }
    __syncthreads();

    // convolve: 4 threads per coarse bin, ~36 taps each, shfl pair-reduce.
    // bin k reads padded fine nodes [16k, 16k+144].
    {
        const int bin = tid >> 2;          // 0..255
        const int q   = tid & 3;
        const int j0  = q * 37;
        const int j1  = (j0 + 37 < TAPS) ? j0 + 37 : TAPS;
        const int base = bin * FSUB;
        float acc = 0.f;
        #pragma unroll 4
        for (int j = j0; j < j1; ++j)
            acc += w[j] * (float)fhs[skew(base + j)];
        acc += __shfl_xor(acc, 1);
        acc += __shfl_xor(acc, 2);
        // non-atomic partial write: each (block, bin) slot written exactly once
        if (q == 0)
            partials[(size_t)blockIdx.x * KBINS + bin] = acc;
    }
}

// reduce 32 per-chunk partials per batch -> out[b,k], apply 1/N
__global__ __launch_bounds__(KBINS)
void reduce_kernel(const float* __restrict__ partials, float* __restrict__ out) {
    const int b = blockIdx.x;
    const int k = threadIdx.x;
    const float* p = partials + (size_t)b * BLK_PER_BATCH * KBINS + k;
    float s = 0.f;
    #pragma unroll
    for (int c = 0; c < BLK_PER_BATCH; ++c)
        s += p[(size_t)c * KBINS];
    out[b * KBINS + k] = s * (1.f / (float)NPB);
}

extern "C" void kernel_launch(void* const* d_in, const int* in_sizes, int n_in,
                              void* d_out, int out_size, void* d_ws, size_t ws_size,
                              hipStream_t stream) {
    const float* x = (const float*)d_in[0];
    float* out = (float*)d_out;
    float* partials = (float*)d_ws;    // 256*256*4 = 256 KB; ws is far larger
    const int B = in_sizes[0] / NPB;   // 8

    hist_kernel<<<B * BLK_PER_BATCH, THREADS, 0, stream>>>(x, partials);
    reduce_kernel<<<B, KBINS, 0, stream>>>(partials, out);
}

// Round 7
// 60.874 us; speedup vs baseline: 1.7797x; 1.0977x over previous
//
#include <hip/hip_runtime.h>
#include <hip/hip_bf16.h>

// SingleDimHistLayer: soft histogram via fine-grid deposit + 145-tap convolution.
//
// Math: out[b,k] = (1/N) * sum_n [ g(u_n - k) - g(u_n - k - 1) ],  g(v)=sigmoid(2.5 v),
//       u = x*256.  Terms negligible outside |u - k - 0.5| <= 4.5 -> 145 fine taps
//       at 1/16 resolution.  Fine index p = round(x*4096) + 64, p in [0,4224].
//
// Round 7: revert to round-2 structure (best: 59.8us) + latency capture.
// Deposit-mechanism search is CLOSED: plain ds_add_u32 (~10.4us/CU, DS-pipe
// lane-serial on distinct addresses) beat device-scope global atomics (+35us),
// wg-scope private global atomics (+25us), and ballot-dedup u16 (+7us; uniform
// data -> ~0 intra-wave collisions -> dedup removes no lane-slots).
// Changes vs round 2, all latency-motivated:
//  (1) register-prefetch the thread's 8 samples BEFORE the init barrier
//      (HBM ~900cyc hides under LDS zeroing instead of serializing);
//  (2) reduce kernel at 1024 threads: 4 threads/bin x 8 loads + shfl_xor
//      (cuts its dependent-load chain 4x);
//  (3) everything else byte-identical.
// Decomposition (7 measurements): dur ~= 41.4 untouchable ws-poison fill
// + deposit 10.4 + conv 1.5 + reduce ~2.5 + load/init/launch ~4.

constexpr int KBINS   = 256;
constexpr int FSUB    = 16;                  // fine nodes per bin
constexpr int LPAD    = 64;                  // left halo (k=0 window reaches f=-64)
constexpr int TAPS    = 145;                 // window f in [16k-64, 16k+80]
// bank-skew addressing: addr = p + (p>>5); max logical p = 4224 -> 4356
constexpr int LDS_FH  = 4360;
constexpr int NPB     = 512 * 512;           // samples per batch
constexpr int BLK_PER_BATCH = 32;            // 8192 samples per block, grid = 256
constexpr int CHUNK   = NPB / BLK_PER_BATCH; // 8192
constexpr int THREADS = 1024;                // 16 waves/CU, 1 block/CU

__device__ __forceinline__ int skew(int p) { return p + (p >> 5); }

__global__ __launch_bounds__(THREADS)
void hist_kernel(const float* __restrict__ x, float* __restrict__ partials) {
    __shared__ unsigned fh[LDS_FH];
    __shared__ float w[TAPS];
    const int tid = threadIdx.x;

    // (1) prefetch this thread's 8 samples before the init barrier: the two
    // global_load_dwordx4 issue here and their ~900cyc latency hides under
    // the LDS zeroing + weight computation below.
    const int b     = blockIdx.x / BLK_PER_BATCH;
    const int chunk = blockIdx.x % BLK_PER_BATCH;
    const float4* xv = (const float4*)(x + (size_t)b * NPB + (size_t)chunk * CHUNK);
    const float4 v0 = xv[tid];
    const float4 v1 = xv[THREADS + tid];

    // zero fine hist
    for (int i = tid; i < LDS_FH; i += THREADS) fh[i] = 0u;

    // conv weights: w[j] = sigmoid(0.15625*(j-64)) - sigmoid(0.15625*(j-80))
    if (tid < TAPS) {
        float a = 0.15625f * (float)(tid - 64);
        float c = 0.15625f * (float)(tid - 80);
        w[tid] = 1.f / (1.f + __expf(-a)) - 1.f / (1.f + __expf(-c));
    }
    __syncthreads();

    // deposit: 8 samples/thread, 1 int LDS atomic per sample.
    // addr = skew((int)(x*4096 + 64.5)) : LPAD + round-to-nearest in one fmaf.
    {
        const float vals[8] = {v0.x, v0.y, v0.z, v0.w, v1.x, v1.y, v1.z, v1.w};
        int addr[8];
        #pragma unroll
        for (int c = 0; c < 8; ++c) {
            float s = fmaf(vals[c], (float)(KBINS * FSUB), (float)LPAD + 0.5f);
            s = fminf(fmaxf(s, 0.f), 4224.f);            // defensive clamp (NaN -> 0)
            addr[c] = skew((int)s);
        }
        #pragma unroll
        for (int c = 0; c < 8; ++c)
            atomicAdd(&fh[addr[c]], 1u);
    }
    __syncthreads();

    // convolve: 4 threads per coarse bin, ~36 taps each, shfl pair-reduce.
    // bin k reads padded fine nodes [16k, 16k+144].
    {
        const int bin = tid >> 2;          // 0..255
        const int q   = tid & 3;
        const int j0  = q * 37;
        const int j1  = (j0 + 37 < TAPS) ? j0 + 37 : TAPS;
        const int base = bin * FSUB;
        float acc = 0.f;
        #pragma unroll 4
        for (int j = j0; j < j1; ++j)
            acc += w[j] * (float)fh[skew(base + j)];
        acc += __shfl_xor(acc, 1);
        acc += __shfl_xor(acc, 2);
        // non-atomic partial write: each (block, bin) slot written exactly once
        if (q == 0)
            partials[(size_t)blockIdx.x * KBINS + bin] = acc;
    }
}

// reduce 32 per-chunk partials per batch -> out[b,k], apply 1/N.
// (2) 1024 threads: 4 threads/bin x 8 strided loads each + shfl pair-reduce.
__global__ __launch_bounds__(THREADS)
void reduce_kernel(const float* __restrict__ partials, float* __restrict__ out) {
    const int b   = blockIdx.x;
    const int tid = threadIdx.x;
    const int bin = tid >> 2;          // 0..255
    const int q   = tid & 3;           // sums partial chunks q*8 .. q*8+7
    const float* p = partials + (size_t)b * BLK_PER_BATCH * KBINS + bin;
    float s = 0.f;
    #pragma unroll
    for (int i = 0; i < 8; ++i)
        s += p[(size_t)(q * 8 + i) * KBINS];
    s += __shfl_xor(s, 1);
    s += __shfl_xor(s, 2);
    if (q == 0)
        out[b * KBINS + bin] = s * (1.f / (float)NPB);
}

extern "C" void kernel_launch(void* const* d_in, const int* in_sizes, int n_in,
                              void* d_out, int out_size, void* d_ws, size_t ws_size,
                              hipStream_t stream) {
    const float* x = (const float*)d_in[0];
    float* out = (float*)d_out;
    float* partials = (float*)d_ws;    // 256*256*4 = 256 KB; ws is far larger
    const int B = in_sizes[0] / NPB;   // 8

    hist_kernel<<<B * BLK_PER_BATCH, THREADS, 0, stream>>>(x, partials);
    reduce_kernel<<<B, THREADS, 0, stream>>>(partials, out);
}

// Round 8
// 59.958 us; speedup vs baseline: 1.8069x; 1.0153x over previous
//
#include <hip/hip_runtime.h>
#include <hip/hip_bf16.h>

// SingleDimHistLayer: soft histogram via fine-grid deposit + 145-tap convolution.
//
// Math: out[b,k] = (1/N) * sum_n [ g(u_n - k) - g(u_n - k - 1) ],  g(v)=sigmoid(2.5 v),
//       u = x*256.  Terms negligible outside |u - k - 0.5| <= 4.5 -> 145 fine taps
//       at 1/16 resolution.  Fine index p = round(x*4096) + 64, p in [0,4224].
//
// FINAL (round 8): byte-identical revert to the round-2 kernel — the best
// measured variant (59.8us). All three search spaces are closed by measurement:
//  - deposit mechanism: plain ds_add_u32 at the DS-pipe lane-serial rate
//    (~3cyc/lane) beats device-scope global atomics (+35us), wg-scope private
//    global atomics (+25us), and ballot-dedup u16 rows (+7us; uniform data has
//    ~0 intra-wave collisions so dedup removes nothing). Bank conflicts are
//    negligible (0.35 cyc/atomic measured).
//  - launch structure: 2-dispatch partials+reduce == memset+atomics (+-0.3us);
//    cooperative single-launch regresses -32us.
//  - latency micro-opts: prefetch-before-init + 4x-wide reduce = +1.1us (noise).
// Structural floor: 41.4us harness ws-poison fill (256MiB @ 6.5TB/s, 82% HBM
// peak, untouchable) + 10.3us deposit (8192 samples/CU x ~3cyc DS-atomic rate)
// + ~5us load/init/conv/reduce/launch ~= 57us; this kernel measures ~59.8.

constexpr int KBINS   = 256;
constexpr int FSUB    = 16;                  // fine nodes per bin
constexpr int LPAD    = 64;                  // left halo (k=0 window reaches f=-64)
constexpr int TAPS    = 145;                 // window f in [16k-64, 16k+80]
// bank-skew addressing: addr = p + (p>>5); max logical p = 4224 -> 4356
constexpr int LDS_FH  = 4360;
constexpr int NPB     = 512 * 512;           // samples per batch
constexpr int BLK_PER_BATCH = 32;            // 8192 samples per block, grid = 256
constexpr int CHUNK   = NPB / BLK_PER_BATCH; // 8192
constexpr int THREADS = 1024;                // 16 waves/CU

__device__ __forceinline__ int skew(int p) { return p + (p >> 5); }

__global__ __launch_bounds__(THREADS)
void hist_kernel(const float* __restrict__ x, float* __restrict__ ws) {
    __shared__ unsigned fh[LDS_FH];
    __shared__ float w[TAPS];
    const int tid = threadIdx.x;

    // zero fine hist
    for (int i = tid; i < LDS_FH; i += THREADS) fh[i] = 0u;

    // conv weights: w[j] = sigmoid(0.15625*(j-64)) - sigmoid(0.15625*(j-80))
    if (tid < TAPS) {
        float a = 0.15625f * (float)(tid - 64);
        float b = 0.15625f * (float)(tid - 80);
        w[tid] = 1.f / (1.f + __expf(-a)) - 1.f / (1.f + __expf(-b));
    }
    __syncthreads();

    const int b     = blockIdx.x / BLK_PER_BATCH;
    const int chunk = blockIdx.x % BLK_PER_BATCH;
    const float4* xv = (const float4*)(x + (size_t)b * NPB + (size_t)chunk * CHUNK);

    // deposit: 8192 samples/block, 2 float4 per thread, 1 int LDS atomic per sample.
    // addr = skew((int)(x*4096 + 64.5)) : LPAD and round-to-nearest folded into fmaf.
    #pragma unroll
    for (int it = 0; it < CHUNK / (4 * THREADS); ++it) {
        float4 v = xv[it * THREADS + tid];
        float vals[4] = {v.x, v.y, v.z, v.w};
        int addr[4];
        #pragma unroll
        for (int c = 0; c < 4; ++c) {
            float s = fmaf(vals[c], (float)(KBINS * FSUB), (float)LPAD + 0.5f);
            s = fminf(fmaxf(s, 0.f), 4224.f);            // defensive clamp (NaN -> 0)
            addr[c] = skew((int)s);
        }
        #pragma unroll
        for (int c = 0; c < 4; ++c)
            atomicAdd(&fh[addr[c]], 1u);
    }
    __syncthreads();

    // convolve: 4 threads per coarse bin, ~36 taps each, shfl pair-reduce.
    // bin k reads padded fine nodes [16k, 16k+144].
    {
        const int bin = tid >> 2;          // 0..255
        const int q   = tid & 3;
        const int j0  = q * 37;
        const int j1  = (j0 + 37 < TAPS) ? j0 + 37 : TAPS;
        const int base = bin * FSUB;
        float acc = 0.f;
        #pragma unroll 4
        for (int j = j0; j < j1; ++j)
            acc += w[j] * (float)fh[skew(base + j)];
        acc += __shfl_xor(acc, 1);
        acc += __shfl_xor(acc, 2);
        // non-atomic partial write: each (block, bin) slot written exactly once
        if (q == 0)
            ws[(size_t)blockIdx.x * KBINS + bin] = acc;
    }
}

// reduce 32 per-chunk partials per batch -> out[b,k], apply 1/N
__global__ __launch_bounds__(KBINS)
void reduce_kernel(const float* __restrict__ ws, float* __restrict__ out) {
    const int b = blockIdx.x;
    const int k = threadIdx.x;
    const float* p = ws + (size_t)b * BLK_PER_BATCH * KBINS + k;
    float s = 0.f;
    #pragma unroll
    for (int c = 0; c < BLK_PER_BATCH; ++c)
        s += p[(size_t)c * KBINS];
    out[b * KBINS + k] = s * (1.f / (float)NPB);
}

extern "C" void kernel_launch(void* const* d_in, const int* in_sizes, int n_in,
                              void* d_out, int out_size, void* d_ws, size_t ws_size,
                              hipStream_t stream) {
    const float* x = (const float*)d_in[0];
    float* out = (float*)d_out;
    float* ws  = (float*)d_ws;     // needs B*32*256*4 = 256 KB; ws is far larger
    const int B = in_sizes[0] / NPB;   // 8

    hist_kernel<<<B * BLK_PER_BATCH, THREADS, 0, stream>>>(x, ws);
    reduce_kernel<<<B, KBINS, 0, stream>>>(ws, out);
}